// Round 4
// baseline (425.353 us; speedup 1.0000x reference)
//
#include <hip/hip_runtime.h>

#define SLEN  2048
#define BATCH 4096

// DPP cross-lane move (VALU-speed, no LDS/lgkm).
template<int CTRL>
__device__ __forceinline__ float dppf(float v) {
    return __int_as_float(
        __builtin_amdgcn_update_dpp(0, __float_as_int(v), CTRL, 0xF, 0xF, true));
}
#define DPP_XOR1 0xB1   // quad_perm [1,0,3,2]
#define DPP_XOR2 0x4E   // quad_perm [2,3,0,1]
#define DPP_XOR3 0x1B   // quad_perm [3,2,1,0]
#define DPP_XOR7 0x141  // ROW_HALF_MIRROR (i ^ 7 within 8)
#define DPP_XOR8 0x128  // ROW_ROR:8 (i ^ 8 within 16)

// packed fp32 FMA (VOP3P, full-rate dual f32)
__device__ __forceinline__ float2 pkfma(float2 a, float2 b, float2 c) {
    float2 d;
    asm("v_pk_fma_f32 %0, %1, %2, %3" : "=v"(d) : "v"(a), "v"(b), "v"(c));
    return d;
}

extern "C" __global__ __launch_bounds__(256, 2)
void bilstm_kernel(const float* __restrict__ x,
                   const float* __restrict__ w_ih_f, const float* __restrict__ w_hh_f,
                   const float* __restrict__ b_ih_f, const float* __restrict__ b_hh_f,
                   const float* __restrict__ w_ih_b, const float* __restrict__ w_hh_b,
                   const float* __restrict__ b_ih_b, const float* __restrict__ b_hh_b,
                   const float* __restrict__ w_out, const float* __restrict__ b_out,
                   const int* __restrict__ future_p,
                   float* __restrict__ out)
{
    const int tid  = threadIdx.x;
    const int wv   = tid >> 6;          // wave in block (0..3)
    const int lane = tid & 63;
    const int e    = lane >> 5;         // batch elem within wave (0..1)
    const int d    = (lane >> 4) & 1;   // 0 = fwd, 1 = bwd
    const int gsel = (lane >> 3) & 1;   // 0: gates (i,f)   1: gates (g,o)
    const int j    = lane & 7;          // hidden index
    const int b    = blockIdx.x * 8 + wv * 2 + e;

    const float* wih_p = d ? w_ih_b : w_ih_f;
    const float* whh_p = d ? w_hh_b : w_hh_f;
    const float* bih_p = d ? b_ih_b : b_ih_f;
    const float* bhh_p = d ? b_hh_b : b_hh_f;

    // Butterfly gather order (pairs): {j^0,j^1 | j^2,j^3 | j^7,j^6 | j^5,j^4}
    const int M[8] = {0, 1, 2, 3, 7, 6, 5, 4};
    float2 whh2[2][4], bini[2];
    float  wih[2];
    #pragma unroll
    for (int gi = 0; gi < 2; ++gi) {
        const int row = (2 * gsel + gi) * 8 + j;   // gate order i,f,g,o
        #pragma unroll
        for (int p = 0; p < 4; ++p) {
            whh2[gi][p].x = whh_p[row * 8 + (j ^ M[2 * p])];
            whh2[gi][p].y = whh_p[row * 8 + (j ^ M[2 * p + 1])];
        }
        wih[gi]    = wih_p[row];
        bini[gi].x = bih_p[row] + bhh_p[row];   // bias folded into first pk_fma
        bini[gi].y = 0.0f;
    }
    // unified activation: act = A*rcp(1 + exp2(K*g)) + B
    //   sigmoid: K=-log2e, A=1, B=0     tanh: K=-2log2e, A=2, B=-1
    const float K0 = gsel ? -2.8853900817779268f : -1.4426950408889634f;
    const float A0 = gsel ? 2.0f : 1.0f;
    const float B0 = gsel ? -1.0f : 0.0f;
    const bool  is_if = (gsel == 0);

    const float wout = w_out[d * 8 + j];
    const float bout = b_out[0];
    const int   fut  = future_p[0];

    __shared__ float o_lds[4][2][2][33];   // [wave][elem][dir][step mod 32] (+pad)

    float c  = 0.0f;
    float hn = 0.0f;

    // x addressing: byte-voffset walks rows; x spans 2^25 bytes so the bwd
    // mod-S wrap is a simple mask (batch offset lives in the low 14 bits).
    const char* xb = (const char*)x;
    unsigned voff = ((unsigned)(d ? (fut & (SLEN - 1)) : 0) * BATCH + (unsigned)b) * 4u;
    const unsigned vdelta = d ? (unsigned)(-(BATCH * 4)) : (unsigned)(BATCH * 4);
    const unsigned vmask  = (unsigned)(SLEN * BATCH * 4 - 1);

    float xv[8], xn[8];
    #pragma unroll
    for (int u = 0; u < 8; ++u) {
        xv[u] = *(const float*)(xb + voff);
        voff = (voff + vdelta) & vmask;
    }

    for (int t0 = 0; t0 < SLEN; t0 += 8) {
        const bool pf = (t0 + 8) < SLEN;
        if (pf) {
            #pragma unroll
            for (int u = 0; u < 8; ++u) {
                xn[u] = *(const float*)(xb + voff);
                voff = (voff + vdelta) & vmask;
            }
        }
        #pragma unroll
        for (int u = 0; u < 8; ++u) {
            // all-gather h across the 8 lanes of this (e,d,gsel): 8 DPP, depth 2
            float v0 = hn;                    // h[j]
            float a1 = dppf<DPP_XOR1>(v0);    // h[j^1]
            float a2 = dppf<DPP_XOR2>(v0);    // h[j^2]
            float a3 = dppf<DPP_XOR3>(v0);    // h[j^3]
            float c7 = dppf<DPP_XOR7>(v0);    // h[j^7]
            float c6 = dppf<DPP_XOR7>(a1);    // h[j^6]
            float c5 = dppf<DPP_XOR7>(a2);    // h[j^5]
            float c4 = dppf<DPP_XOR7>(a3);    // h[j^4]
            float2 P0; P0.x = v0; P0.y = a1;
            float2 P1; P1.x = a2; P1.y = a3;
            float2 P2; P2.x = c7; P2.y = c6;
            float2 P3; P3.x = c5; P3.y = c4;

            float g[2];
            #pragma unroll
            for (int gi = 0; gi < 2; ++gi) {
                float2 acc = pkfma(P0, whh2[gi][0], bini[gi]);
                acc = pkfma(P1, whh2[gi][1], acc);
                acc = pkfma(P2, whh2[gi][2], acc);
                acc = pkfma(P3, whh2[gi][3], acc);
                g[gi] = fmaf(xv[u], wih[gi], acc.x + acc.y);
            }
            // act0: i (sigmoid) or g (tanh) via unified formula; act1: f or o (sigmoid)
            float t0a  = __builtin_amdgcn_exp2f(K0 * g[0]);
            float act0 = fmaf(A0, __builtin_amdgcn_rcpf(1.0f + t0a), B0);
            float t1a  = __builtin_amdgcn_exp2f(-1.4426950408889634f * g[1]);
            float act1 = __builtin_amdgcn_rcpf(1.0f + t1a);

            // exchange with gsel-partner (xor8)
            float e0 = dppf<DPP_XOR8>(act0);   // partner's act0
            float e1 = dppf<DPP_XOR8>(act1);   // partner's act1

            // gsel0: own=(ia,fa) partner=(ga,oa); gsel1: own=(ga,oa) partner=(ia,fa)
            float fa = is_if ? act1 : e1;
            float oa = is_if ? e1   : act1;
            float ig = act0 * e0;              // ia*ga (commutative, both halves equal)
            c = fmaf(fa, c, ig);
            float tt = __builtin_amdgcn_exp2f(-2.8853900817779268f * c);
            float T  = fmaf(2.0f, __builtin_amdgcn_rcpf(1.0f + tt), -1.0f);
            hn = oa * T;

            // per-(e,d) output partial: reduce over the 8 j-lanes
            float p = hn * wout;
            p += dppf<DPP_XOR1>(p);
            p += dppf<DPP_XOR2>(p);
            p += dppf<DPP_XOR7>(p);
            if ((lane & 15) == 0) o_lds[wv][e][d][(t0 + u) & 31] = p;
        }
        // coalesced flush of 32 outputs per elem (sum dir partials here)
        if ((t0 & 31) == 24) {
            __builtin_amdgcn_wave_barrier();
            const int le = lane >> 5, s = lane & 31;
            const int bb = blockIdx.x * 8 + wv * 2 + le;
            const int s0 = t0 - 24;
            float v = o_lds[wv][le][0][s] + o_lds[wv][le][1][s];
            out[bb * SLEN + s0 + s] = v + bout;
            __builtin_amdgcn_wave_barrier();
        }
        if (pf) {
            #pragma unroll
            for (int u = 0; u < 8; ++u) xv[u] = xn[u];
        }
    }
}

extern "C" void kernel_launch(void* const* d_in, const int* in_sizes, int n_in,
                              void* d_out, int out_size, void* d_ws, size_t ws_size,
                              hipStream_t stream) {
    const float* xp     = (const float*)d_in[0];
    const float* wihf   = (const float*)d_in[1];
    const float* whhf   = (const float*)d_in[2];
    const float* bihf   = (const float*)d_in[3];
    const float* bhhf   = (const float*)d_in[4];
    const float* wihb   = (const float*)d_in[5];
    const float* whhb   = (const float*)d_in[6];
    const float* bihb   = (const float*)d_in[7];
    const float* bhhb   = (const float*)d_in[8];
    const float* wo     = (const float*)d_in[9];
    const float* bo     = (const float*)d_in[10];
    const int*   futp   = (const int*)d_in[11];
    float*       outp   = (float*)d_out;

    dim3 grid(BATCH / 8);
    dim3 block(256);
    hipLaunchKernelGGL(bilstm_kernel, grid, block, 0, stream,
                       xp, wihf, whhf, bihf, bhhf, wihb, whhb, bihb, bhhb,
                       wo, bo, futp, outp);
}

// Round 5
// 340.775 us; speedup vs baseline: 1.2482x; 1.2482x over previous
//
#include <hip/hip_runtime.h>

#define SLEN  2048
#define BATCH 4096

// Single-instruction DPP lane move (compiler manages DPP hazards).
template<int CTRL>
__device__ __forceinline__ float dppf(float v) {
#if __has_builtin(__builtin_amdgcn_mov_dpp)
    return __int_as_float(
        __builtin_amdgcn_mov_dpp(__float_as_int(v), CTRL, 0xF, 0xF, true));
#else
    return __int_as_float(
        __builtin_amdgcn_update_dpp(0, __float_as_int(v), CTRL, 0xF, 0xF, true));
#endif
}
#define DPP_XOR1 0xB1   // quad_perm [1,0,3,2]
#define DPP_XOR2 0x4E   // quad_perm [2,3,0,1]
#define DPP_XOR3 0x1B   // quad_perm [3,2,1,0]
#define DPP_XOR7 0x141  // ROW_HALF_MIRROR (i ^ 7 within 8)

// Packed fp32 FMA, in-place accumulator (tied operand -> no reg-copy movs).
__device__ __forceinline__ void pkfma_acc(float2& acc, float2 a, float2 b) {
    asm("v_pk_fma_f32 %0, %1, %2, %0" : "+v"(acc) : "v"(a), "v"(b));
}
// acc += bcast(h2[q]) * w   (op_sel dword-broadcast of one half of h2)
template<int Q>
__device__ __forceinline__ void pkfma_bc(float2& acc, float2 h2, float2 w) {
    if constexpr (Q == 0)
        asm("v_pk_fma_f32 %0, %1, %2, %0 op_sel:[0,0,0] op_sel_hi:[0,1,1]"
            : "+v"(acc) : "v"(h2), "v"(w));
    else
        asm("v_pk_fma_f32 %0, %1, %2, %0 op_sel:[1,0,0] op_sel_hi:[1,1,1]"
            : "+v"(acc) : "v"(h2), "v"(w));
}

extern "C" __global__ __launch_bounds__(256, 1)
void bilstm_kernel(const float* __restrict__ x,
                   const float* __restrict__ w_ih_f, const float* __restrict__ w_hh_f,
                   const float* __restrict__ b_ih_f, const float* __restrict__ b_hh_f,
                   const float* __restrict__ w_ih_b, const float* __restrict__ w_hh_b,
                   const float* __restrict__ b_ih_b, const float* __restrict__ b_hh_b,
                   const float* __restrict__ w_out, const float* __restrict__ b_out,
                   const int* __restrict__ future_p,
                   float* __restrict__ out)
{
    const int tid  = threadIdx.x;
    const int wv   = tid >> 6;     // wave in block (0..3)
    const int lane = tid & 63;
    const int e    = lane >> 4;    // batch elem within wave (0..3)
    const int r    = lane & 15;
    const int d    = r >> 3;       // 0 = fwd, 1 = bwd
    const int j    = r & 7;        // hidden index
    const int b    = blockIdx.x * 16 + wv * 4 + e;

    const float* wih_p = d ? w_ih_b : w_ih_f;
    const float* whh_p = d ? w_hh_b : w_hh_f;
    const float* bih_p = d ? b_ih_b : b_ih_f;
    const float* bhh_p = d ? b_hh_b : b_hh_f;

    // Gate rows (torch order): i=0..7, f=8..15, g=16..23, o=24..31.
    // Prescale so gates emerge as exp2 arguments:
    //   sigmoid(v) = rcp(1 + exp2(-log2e * v)),  tanh(v) = 2*rcp(1+exp2(-2log2e*v)) - 1
    const float SI = -1.4426950408889634f;   // i, f, o rows
    const float SG = -2.8853900817779268f;   // g row

    // Butterfly slot -> h index xor mask (pairs: lo,hi of P0..P3)
    const int M[8] = {0, 1, 2, 3, 7, 6, 5, 4};
    float2 Wif[8], Wgo[8], wih_if, wih_go, b_if, b_go;
    #pragma unroll
    for (int m = 0; m < 8; ++m) {
        const int idx = j ^ M[m];
        Wif[m].x = SI * whh_p[(0 + j) * 8 + idx];     // gate i
        Wif[m].y = SI * whh_p[(8 + j) * 8 + idx];     // gate f
        Wgo[m].x = SG * whh_p[(16 + j) * 8 + idx];    // gate g
        Wgo[m].y = SI * whh_p[(24 + j) * 8 + idx];    // gate o
    }
    wih_if.x = SI * wih_p[0 + j];   wih_if.y = SI * wih_p[8 + j];
    wih_go.x = SG * wih_p[16 + j];  wih_go.y = SI * wih_p[24 + j];
    b_if.x = SI * (bih_p[0 + j]  + bhh_p[0 + j]);
    b_if.y = SI * (bih_p[8 + j]  + bhh_p[8 + j]);
    b_go.x = SG * (bih_p[16 + j] + bhh_p[16 + j]);
    b_go.y = SI * (bih_p[24 + j] + bhh_p[24 + j]);

    const float wout = w_out[d * 8 + j];
    const float bout = b_out[0];
    const int   fut  = future_p[0];

    __shared__ float o_lds[4][4][2][33];   // [wave][elem][dir][step mod 32] (+pad)

    float c  = 0.0f;
    float hn = 0.0f;

    // x addressing: byte-voffset walks rows; x spans 2^25 bytes so the bwd
    // mod-S wrap is a simple mask (batch offset lives in the low 14 bits).
    const char* xb = (const char*)x;
    unsigned voff = ((unsigned)(d ? (fut & (SLEN - 1)) : 0) * BATCH + (unsigned)b) * 4u;
    const unsigned vdelta = d ? (unsigned)(-(BATCH * 4)) : (unsigned)(BATCH * 4);
    const unsigned vmask  = (unsigned)(SLEN * BATCH * 4 - 1);

    float xv[8], xn[8];
    #pragma unroll
    for (int u = 0; u < 8; ++u) {
        xv[u] = *(const float*)(xb + voff);
        voff = (voff + vdelta) & vmask;
    }

    for (int t0 = 0; t0 < SLEN; t0 += 8) {
        const bool pf = (t0 + 8) < SLEN;
        if (pf) {
            #pragma unroll
            for (int u = 0; u < 8; ++u) {
                xn[u] = *(const float*)(xb + voff);
                voff = (voff + vdelta) & vmask;
            }
        }
        #pragma unroll
        for (int u = 0; u < 8; ++u) {
            // all-gather h across the 8 j-lanes of this (e,d): 7 DPP movs
            float2 P0, P1, P2, P3;
            P0.x = hn;                      // h[j]
            P0.y = dppf<DPP_XOR1>(hn);      // h[j^1]
            P1.x = dppf<DPP_XOR2>(hn);      // h[j^2]
            P1.y = dppf<DPP_XOR3>(hn);      // h[j^3]
            P2.x = dppf<DPP_XOR7>(P0.x);    // h[j^7]
            P2.y = dppf<DPP_XOR7>(P0.y);    // h[j^6]
            P3.x = dppf<DPP_XOR7>(P1.x);    // h[j^5]
            P3.y = dppf<DPP_XOR7>(P1.y);    // h[j^4]

            float2 xv2; xv2.x = xv[u]; xv2.y = xv[u];
            float2 acc_if = b_if, acc_go = b_go;
            pkfma_acc(acc_if, xv2, wih_if);
            pkfma_acc(acc_go, xv2, wih_go);
            pkfma_bc<0>(acc_if, P0, Wif[0]);  pkfma_bc<1>(acc_if, P0, Wif[1]);
            pkfma_bc<0>(acc_if, P1, Wif[2]);  pkfma_bc<1>(acc_if, P1, Wif[3]);
            pkfma_bc<0>(acc_if, P2, Wif[4]);  pkfma_bc<1>(acc_if, P2, Wif[5]);
            pkfma_bc<0>(acc_if, P3, Wif[6]);  pkfma_bc<1>(acc_if, P3, Wif[7]);
            pkfma_bc<0>(acc_go, P0, Wgo[0]);  pkfma_bc<1>(acc_go, P0, Wgo[1]);
            pkfma_bc<0>(acc_go, P1, Wgo[2]);  pkfma_bc<1>(acc_go, P1, Wgo[3]);
            pkfma_bc<0>(acc_go, P2, Wgo[4]);  pkfma_bc<1>(acc_go, P2, Wgo[5]);
            pkfma_bc<0>(acc_go, P3, Wgo[6]);  pkfma_bc<1>(acc_go, P3, Wgo[7]);

            // activations (gates pre-scaled: direct exp2)
            float ia = __builtin_amdgcn_rcpf(1.0f + __builtin_amdgcn_exp2f(acc_if.x));
            float fa = __builtin_amdgcn_rcpf(1.0f + __builtin_amdgcn_exp2f(acc_if.y));
            float rg = __builtin_amdgcn_rcpf(1.0f + __builtin_amdgcn_exp2f(acc_go.x));
            float oa = __builtin_amdgcn_rcpf(1.0f + __builtin_amdgcn_exp2f(acc_go.y));
            float ga = fmaf(2.0f, rg, -1.0f);

            c = fmaf(fa, c, ia * ga);
            float tc = __builtin_amdgcn_exp2f(SG * c);
            float T  = fmaf(2.0f, __builtin_amdgcn_rcpf(1.0f + tc), -1.0f);
            hn = oa * T;

            // per-(e,d) output partial: reduce over the 8 j-lanes
            float p = hn * wout;
            p += dppf<DPP_XOR1>(p);
            p += dppf<DPP_XOR2>(p);
            p += dppf<DPP_XOR7>(p);
            if ((r & 7) == 0) o_lds[wv][e][d][(t0 + u) & 31] = p;
        }
        // coalesced flush of 32 outputs per elem (sum dir partials here)
        if ((t0 & 31) == 24) {
            __builtin_amdgcn_wave_barrier();
            const int le = lane >> 4, lo = lane & 15;
            const int bb = blockIdx.x * 16 + wv * 4 + le;
            const int s0 = t0 - 24;
            float v0 = o_lds[wv][le][0][lo]      + o_lds[wv][le][1][lo];
            float v1 = o_lds[wv][le][0][lo + 16] + o_lds[wv][le][1][lo + 16];
            out[bb * SLEN + s0 + lo]      = v0 + bout;
            out[bb * SLEN + s0 + 16 + lo] = v1 + bout;
            __builtin_amdgcn_wave_barrier();
        }
        if (pf) {
            #pragma unroll
            for (int u = 0; u < 8; ++u) xv[u] = xn[u];
        }
    }
}

extern "C" void kernel_launch(void* const* d_in, const int* in_sizes, int n_in,
                              void* d_out, int out_size, void* d_ws, size_t ws_size,
                              hipStream_t stream) {
    const float* xp     = (const float*)d_in[0];
    const float* wihf   = (const float*)d_in[1];
    const float* whhf   = (const float*)d_in[2];
    const float* bihf   = (const float*)d_in[3];
    const float* bhhf   = (const float*)d_in[4];
    const float* wihb   = (const float*)d_in[5];
    const float* whhb   = (const float*)d_in[6];
    const float* bihb   = (const float*)d_in[7];
    const float* bhhb   = (const float*)d_in[8];
    const float* wo     = (const float*)d_in[9];
    const float* bo     = (const float*)d_in[10];
    const int*   futp   = (const int*)d_in[11];
    float*       outp   = (float*)d_out;

    dim3 grid(BATCH / 16);
    dim3 block(256);
    hipLaunchKernelGGL(bilstm_kernel, grid, block, 0, stream,
                       xp, wihf, whhf, bihf, bhhf, wihb, whhb, bihb, bhhb,
                       wo, bo, futp, outp);
}

// Round 7
// 297.822 us; speedup vs baseline: 1.4282x; 1.1442x over previous
//
#include <hip/hip_runtime.h>

#define SLEN  2048
#define BATCH 4096

// DPP cross-lane move (VALU-speed, no LDS/lgkm).
template<int CTRL>
__device__ __forceinline__ float dppf(float v) {
    return __int_as_float(
        __builtin_amdgcn_update_dpp(0, __float_as_int(v), CTRL, 0xF, 0xF, true));
}
#define DPP_XOR1 0xB1   // quad_perm [1,0,3,2]
#define DPP_XOR2 0x4E   // quad_perm [2,3,0,1]
#define DPP_XOR3 0x1B   // quad_perm [3,2,1,0]
#define DPP_XOR7 0x141  // ROW_HALF_MIRROR (i ^ 7 within 8)

// dst = bcast(x2[Q]) * w + b   (op_sel dword-broadcast from a pair; fresh dest)
template<int Q>
__device__ __forceinline__ float2 pkfma_init(float2 x2, float2 w, float2 b) {
    float2 dst;
    if constexpr (Q == 0)
        asm("v_pk_fma_f32 %0, %1, %2, %3 op_sel:[0,0,0] op_sel_hi:[0,1,1]"
            : "=v"(dst) : "v"(x2), "v"(w), "v"(b));
    else
        asm("v_pk_fma_f32 %0, %1, %2, %3 op_sel:[1,0,0] op_sel_hi:[1,1,1]"
            : "=v"(dst) : "v"(x2), "v"(w), "v"(b));
    return dst;
}
// acc += bcast(h2[Q]) * w  (op_sel dword-broadcast; tied accumulator)
template<int Q>
__device__ __forceinline__ void pkfma_bc(float2& acc, float2 h2, float2 w) {
    if constexpr (Q == 0)
        asm("v_pk_fma_f32 %0, %1, %2, %0 op_sel:[0,0,0] op_sel_hi:[0,1,1]"
            : "+v"(acc) : "v"(h2), "v"(w));
    else
        asm("v_pk_fma_f32 %0, %1, %2, %0 op_sel:[1,0,0] op_sel_hi:[1,1,1]"
            : "+v"(acc) : "v"(h2), "v"(w));
}

extern "C" __global__ __launch_bounds__(256, 1)
void bilstm_kernel(const float* __restrict__ x,
                   const float* __restrict__ w_ih_f, const float* __restrict__ w_hh_f,
                   const float* __restrict__ b_ih_f, const float* __restrict__ b_hh_f,
                   const float* __restrict__ w_ih_b, const float* __restrict__ w_hh_b,
                   const float* __restrict__ b_ih_b, const float* __restrict__ b_hh_b,
                   const float* __restrict__ w_out, const float* __restrict__ b_out,
                   const int* __restrict__ future_p,
                   float* __restrict__ out)
{
    const int tid  = threadIdx.x;
    const int wv   = tid >> 6;     // wave in block (0..3)
    const int lane = tid & 63;
    const int e    = lane >> 4;    // batch elem within wave (0..3)
    const int r    = lane & 15;
    const int d    = r >> 3;       // 0 = fwd, 1 = bwd
    const int j    = r & 7;        // hidden index
    const int b    = blockIdx.x * 16 + wv * 4 + e;

    const float* wih_p = d ? w_ih_b : w_ih_f;
    const float* whh_p = d ? w_hh_b : w_hh_f;
    const float* bih_p = d ? b_ih_b : b_ih_f;
    const float* bhh_p = d ? b_hh_b : b_hh_f;

    // Prescale so gate accumulators emerge as exp2 arguments:
    //   sigmoid(v) = 1/(1+exp2(-log2e*v)),  tanh(v) = (1-E)/(1+E), E=exp2(-2log2e*v)
    const float SI = -1.4426950408889634f;   // i, f, o rows
    const float SG = -2.8853900817779268f;   // g row

    // Butterfly slot -> h index xor mask (pairs: lo,hi of P0..P3)
    const int M[8] = {0, 1, 2, 3, 7, 6, 5, 4};
    float2 Wif[8], Wgo[8], wih_if, wih_go, b_if, b_go;
    #pragma unroll
    for (int m = 0; m < 8; ++m) {
        const int idx = j ^ M[m];
        Wif[m].x = SI * whh_p[(0 + j) * 8 + idx];     // gate i
        Wif[m].y = SI * whh_p[(8 + j) * 8 + idx];     // gate f
        Wgo[m].x = SG * whh_p[(16 + j) * 8 + idx];    // gate g
        Wgo[m].y = SI * whh_p[(24 + j) * 8 + idx];    // gate o
    }
    wih_if.x = SI * wih_p[0 + j];   wih_if.y = SI * wih_p[8 + j];
    wih_go.x = SG * wih_p[16 + j];  wih_go.y = SI * wih_p[24 + j];
    b_if.x = SI * (bih_p[0 + j]  + bhh_p[0 + j]);
    b_if.y = SI * (bih_p[8 + j]  + bhh_p[8 + j]);
    b_go.x = SG * (bih_p[16 + j] + bhh_p[16 + j]);
    b_go.y = SI * (bih_p[24 + j] + bhh_p[24 + j]);

    const float wout = w_out[d * 8 + j];
    const float bout = b_out[0];
    const int   fut  = future_p[0];

    // [wave][row = e*2+d][72]: slots 0..31 = outputs (written by j==0 lane),
    // slots 32+j+s = dump region for the non-writer lanes.
    __shared__ float o_lds[4][8][72];
    float* o_ptr = &o_lds[wv][e * 2 + d][(j == 0) ? 0 : (32 + j)];
    float* o_base = &o_lds[wv][0][0];

    float c  = 0.0f;
    float hn = 0.0f;

    // x addressing: byte-voffset walks rows; x spans 2^25 bytes so the bwd
    // mod-S wrap is a simple mask (batch offset lives in the low 14 bits).
    const char* xb = (const char*)x;
    unsigned voff = ((unsigned)(d ? (fut & (SLEN - 1)) : 0) * BATCH + (unsigned)b) * 4u;
    const unsigned vdelta = d ? (unsigned)(-(BATCH * 4)) : (unsigned)(BATCH * 4);
    const unsigned vmask  = (unsigned)(SLEN * BATCH * 4 - 1);

    // x pairs: xa2[p] holds steps (2p, 2p+1) of the current 8-step block
    float2 xa2[4], xb2[4];
    #pragma unroll
    for (int p = 0; p < 4; ++p) {
        xa2[p].x = *(const float*)(xb + voff); voff = (voff + vdelta) & vmask;
        xa2[p].y = *(const float*)(xb + voff); voff = (voff + vdelta) & vmask;
    }

    // acc_if/acc_go arrive pre-initialized with x*w_ih + bias
    auto STEP = [&](float2 acc_if, float2 acc_go, int slot) {
        // all-gather h across the 8 j-lanes of this (e,d): 7 DPP movs
        float2 P0, P1, P2, P3;
        P0.x = hn;                      // h[j]
        P0.y = dppf<DPP_XOR1>(hn);      // h[j^1]
        P1.x = dppf<DPP_XOR2>(hn);      // h[j^2]
        P1.y = dppf<DPP_XOR3>(hn);      // h[j^3]
        P2.x = dppf<DPP_XOR7>(P0.x);    // h[j^7]
        P2.y = dppf<DPP_XOR7>(P0.y);    // h[j^6]
        P3.x = dppf<DPP_XOR7>(P1.x);    // h[j^5]
        P3.y = dppf<DPP_XOR7>(P1.y);    // h[j^4]

        pkfma_bc<0>(acc_if, P0, Wif[0]);  pkfma_bc<1>(acc_if, P0, Wif[1]);
        pkfma_bc<0>(acc_if, P1, Wif[2]);  pkfma_bc<1>(acc_if, P1, Wif[3]);
        pkfma_bc<0>(acc_if, P2, Wif[4]);  pkfma_bc<1>(acc_if, P2, Wif[5]);
        pkfma_bc<0>(acc_if, P3, Wif[6]);  pkfma_bc<1>(acc_if, P3, Wif[7]);
        pkfma_bc<0>(acc_go, P0, Wgo[0]);  pkfma_bc<1>(acc_go, P0, Wgo[1]);
        pkfma_bc<0>(acc_go, P1, Wgo[2]);  pkfma_bc<1>(acc_go, P1, Wgo[3]);
        pkfma_bc<0>(acc_go, P2, Wgo[4]);  pkfma_bc<1>(acc_go, P2, Wgo[5]);
        pkfma_bc<0>(acc_go, P3, Wgo[6]);  pkfma_bc<1>(acc_go, P3, Wgo[7]);

        // activations with merged rcps:
        //   ia*ga = (2-eg1)/(ei1*eg1);  fa,oa share rcp(ef1*eo1)
        float ei = __builtin_amdgcn_exp2f(acc_if.x);
        float ef = __builtin_amdgcn_exp2f(acc_if.y);
        float eg = __builtin_amdgcn_exp2f(acc_go.x);
        float eo = __builtin_amdgcn_exp2f(acc_go.y);
        float ei1 = 1.0f + ei, ef1 = 1.0f + ef, eg1 = 1.0f + eg, eo1 = 1.0f + eo;
        float riu = __builtin_amdgcn_rcpf(ei1 * eg1);
        float ig  = (2.0f - eg1) * riu;          // = ia*ga
        float rv  = __builtin_amdgcn_rcpf(ef1 * eo1);
        float fa  = rv * eo1;
        float oa  = rv * ef1;
        c = fmaf(fa, c, ig);
        float tc = __builtin_amdgcn_exp2f(SG * c);
        float rt = __builtin_amdgcn_rcpf(1.0f + tc);
        float T  = fmaf(2.0f, rt, -1.0f);
        hn = oa * T;

        // per-(e,d) output partial: reduce over the 8 j-lanes, dump-write
        float p = hn * wout;
        p += dppf<DPP_XOR1>(p);
        p += dppf<DPP_XOR2>(p);
        p += dppf<DPP_XOR7>(p);
        o_ptr[slot] = p;
    };

    for (int T = 0; T < SLEN; T += 32) {
        #pragma unroll
        for (int blk = 0; blk < 4; ++blk) {
            // prefetch next 8 x values into the other bank
            #pragma unroll
            for (int p = 0; p < 4; ++p) {
                if (blk & 1) {
                    xa2[p].x = *(const float*)(xb + voff); voff = (voff + vdelta) & vmask;
                    xa2[p].y = *(const float*)(xb + voff); voff = (voff + vdelta) & vmask;
                } else {
                    xb2[p].x = *(const float*)(xb + voff); voff = (voff + vdelta) & vmask;
                    xb2[p].y = *(const float*)(xb + voff); voff = (voff + vdelta) & vmask;
                }
            }
            #pragma unroll
            for (int p = 0; p < 4; ++p) {
                float2 x2 = (blk & 1) ? xb2[p] : xa2[p];
                STEP(pkfma_init<0>(x2, wih_if, b_if),
                     pkfma_init<0>(x2, wih_go, b_go), blk * 8 + 2 * p);
                STEP(pkfma_init<1>(x2, wih_if, b_if),
                     pkfma_init<1>(x2, wih_go, b_go), blk * 8 + 2 * p + 1);
            }
        }
        // coalesced flush of 32 outputs per elem (sum dir partials here)
        __builtin_amdgcn_wave_barrier();
        {
            const int le = lane >> 4, lo = lane & 15;
            const int bb = blockIdx.x * 16 + wv * 4 + le;
            float v0 = o_base[(le * 2 + 0) * 72 + lo]      + o_base[(le * 2 + 1) * 72 + lo];
            float v1 = o_base[(le * 2 + 0) * 72 + lo + 16] + o_base[(le * 2 + 1) * 72 + lo + 16];
            out[bb * SLEN + T + lo]      = v0 + bout;
            out[bb * SLEN + T + 16 + lo] = v1 + bout;
        }
        __builtin_amdgcn_wave_barrier();
    }
}

extern "C" void kernel_launch(void* const* d_in, const int* in_sizes, int n_in,
                              void* d_out, int out_size, void* d_ws, size_t ws_size,
                              hipStream_t stream) {
    const float* xp     = (const float*)d_in[0];
    const float* wihf   = (const float*)d_in[1];
    const float* whhf   = (const float*)d_in[2];
    const float* bihf   = (const float*)d_in[3];
    const float* bhhf   = (const float*)d_in[4];
    const float* wihb   = (const float*)d_in[5];
    const float* whhb   = (const float*)d_in[6];
    const float* bihb   = (const float*)d_in[7];
    const float* bhhb   = (const float*)d_in[8];
    const float* wo     = (const float*)d_in[9];
    const float* bo     = (const float*)d_in[10];
    const int*   futp   = (const int*)d_in[11];
    float*       outp   = (float*)d_out;

    dim3 grid(BATCH / 16);
    dim3 block(256);
    hipLaunchKernelGGL(bilstm_kernel, grid, block, 0, stream,
                       xp, wihf, whhf, bihf, bhhf, wihb, whhb, bihb, bhhb,
                       wo, bo, futp, outp);
}